// Round 12
// baseline (471.064 us; speedup 1.0000x reference)
//
#include <hip/hip_runtime.h>

#define B_ 1024
#define S_ 256
#define D_ 128
#define K_ 26
#define EST 27   // e_lds row stride (odd -> conflict-free)

// Fused CRF: one block (4 waves) per batch element.
// Phase A: 4 waves cooperatively compute emissions into LDS (bit-identical math
//          to the proven split emis_kernel: same k-groups, same acc order).
// Phase B: wave 0 alone runs the r11-proven recurrence + speculative backtrack
//          (no barriers; single-wave in-order LDS + compiler fences).
__global__ __launch_bounds__(256, 4) void crf_fused(
    const float* __restrict__ X, const float* __restrict__ W,
    const float* __restrict__ Tr, int* __restrict__ out)
{
  __shared__ float e_lds[S_ * EST];                // 27648 B
  __shared__ __align__(16) float pub[28];          //   112 B
  __shared__ unsigned char bp[K_][260];            //  6760 B
  __shared__ unsigned char spec[K_][132];          //  3432 B
  __shared__ int path_s[S_];                       //  1024 B  (~38.9 KB total)

  const int tid  = threadIdx.x;
  const int lane = tid & 63;
  const int b    = blockIdx.x;

  // ---------------- Phase A: emissions into e_lds ----------------
  {
    const int gu = __builtin_amdgcn_readfirstlane(tid >> 6);   // wave id, uniform
    const int k0 = (gu < 2) ? 7 * gu : 6 * gu + 2;             // 0,7,14,20
    const int kn = (gu < 2) ? 7 : 6;
    const float* xb = X + (size_t)b * (S_ * D_);

    for (int q = 0; q < 4; ++q) {
      const int t = q * 64 + lane;
      float acc[7][4];
#pragma unroll
      for (int kk = 0; kk < 7; ++kk)
#pragma unroll
        for (int c = 0; c < 4; ++c) acc[kk][c] = 0.f;

#pragma unroll
      for (int dc = 0; dc < 16; ++dc) {
        const float4* xp = reinterpret_cast<const float4*>(xb + t * D_ + dc * 8);
        float4 a0 = xp[0];
        float4 a1 = xp[1];
        float xv[8] = {a0.x, a0.y, a0.z, a0.w, a1.x, a1.y, a1.z, a1.w};
#pragma unroll
        for (int kk = 0; kk < 7; ++kk) {
          int k = k0 + kk; k = (k > K_ - 1) ? (K_ - 1) : k;
          const float* wr = W + k * D_ + dc * 8;   // wave-uniform -> s_load
#pragma unroll
          for (int dd = 0; dd < 8; ++dd)
            acc[kk][dd & 3] = fmaf(xv[dd], wr[dd], acc[kk][dd & 3]);
        }
      }
#pragma unroll
      for (int kk = 0; kk < 7; ++kk)
        if (kk < kn)
          e_lds[t * EST + k0 + kk] =
              (acc[kk][0] + acc[kk][1]) + (acc[kk][2] + acc[kk][3]);
    }
  }
  __syncthreads();                 // e_lds complete and visible
  if (tid >= 64) return;           // waves 1-3 done; wave 0 continues barrier-free

  // ---------------- Phase B: recurrence (r11 body, stride EST) ----------------
  const int jc = (lane < K_) ? lane : (K_ - 1);

  float tc[K_];
#pragma unroll
  for (int i = 0; i < K_; ++i) tc[i] = Tr[i * K_ + jc];

  float delta = e_lds[jc];                          // t = 0
  if (lane < 28) pub[lane] = -3.4e38f;
  if (lane < K_) pub[lane] = delta;
  asm volatile("" ::: "memory");

  float4 raw[7];
  {
    const float4* p = reinterpret_cast<const float4*>(pub);
#pragma unroll
    for (int q = 0; q < 7; ++q) raw[q] = p[q];      // uniform broadcast reads
  }
  float ev_cur = e_lds[EST + jc];                   // e[1][jc], consumed at t=1

  for (int t = 1; t < S_; ++t) {
    float v[K_ + 2];
#pragma unroll
    for (int q = 0; q < 7; ++q) {
      v[4 * q + 0] = raw[q].x;
      v[4 * q + 1] = raw[q].y;
      v[4 * q + 2] = raw[q].z;
      v[4 * q + 3] = raw[q].w;
    }
#pragma unroll
    for (int i = 0; i < K_; ++i) v[i] += tc[i];

    // value path: max3 tree (exact)
    float m[9];
#pragma unroll
    for (int i = 0; i < 8; ++i) m[i] = fmaxf(fmaxf(v[3 * i], v[3 * i + 1]), v[3 * i + 2]);
    m[8] = fmaxf(v[24], v[25]);
    float n0 = fmaxf(fmaxf(m[0], m[1]), m[2]);
    float n1 = fmaxf(fmaxf(m[3], m[4]), m[5]);
    float n2 = fmaxf(fmaxf(m[6], m[7]), m[8]);
    float best = fmaxf(fmaxf(n0, n1), n2);

    delta = best + ev_cur;                          // same op order as reference

    // publish delta(t); compiler fence; issue next gather (same-wave DS in-order)
    if (lane < K_) pub[lane] = delta;
    asm volatile("" ::: "memory");
    {
      const float4* p = reinterpret_cast<const float4*>(pub);
#pragma unroll
      for (int q = 0; q < 7; ++q) raw[q] = p[q];
    }

    int tn = (t + 1 < S_) ? (t + 1) : (S_ - 1);
    ev_cur = e_lds[tn * EST + jc];

    // argmax path (fills gather latency): first i with v[i]==best
    int c[K_];
#pragma unroll
    for (int i = 0; i < K_; ++i) c[i] = (v[i] == best) ? i : 63;
    int q9[9];
#pragma unroll
    for (int i = 0; i < 8; ++i) {
      int a = c[3 * i] < c[3 * i + 1] ? c[3 * i] : c[3 * i + 1];
      q9[i] = a < c[3 * i + 2] ? a : c[3 * i + 2];
    }
    q9[8] = c[24] < c[25] ? c[24] : c[25];
    int r0 = q9[0] < q9[1] ? q9[0] : q9[1]; r0 = r0 < q9[2] ? r0 : q9[2];
    int r1 = q9[3] < q9[4] ? q9[3] : q9[4]; r1 = r1 < q9[5] ? r1 : q9[5];
    int r2 = q9[6] < q9[7] ? q9[6] : q9[7]; r2 = r2 < q9[8] ? r2 : q9[8];
    int idx = r0 < r1 ? r0 : r1; idx = idx < r2 ? idx : r2;

    if (lane < K_) bp[lane][t] = (unsigned char)idx;
  }

  // final first-argmax over delta(255)
  int last;
  {
    float v[K_];
#pragma unroll
    for (int q = 0; q < 7; ++q) {
      if (4 * q + 0 < K_) v[4 * q + 0] = raw[q].x;
      if (4 * q + 1 < K_) v[4 * q + 1] = raw[q].y;
      if (4 * q + 2 < K_) v[4 * q + 2] = raw[q].z;
      if (4 * q + 3 < K_) v[4 * q + 3] = raw[q].w;
    }
    float bf = v[0];
#pragma unroll
    for (int i = 1; i < K_; ++i) bf = fmaxf(bf, v[i]);
    int iA = 63;
#pragma unroll
    for (int i = K_ - 1; i >= 0; --i) iA = (v[i] == bf) ? i : iA;
    last = iA;
  }

  // in-wave ordering: bp writes drained before backtrack reads
  asm volatile("s_waitcnt lgkmcnt(0)" ::: "memory");

  // backtrack: real chain (lane 63) t=255..129 concurrent with 26 speculative
  // chains (lanes 0..25) covering t=128..1 for every possible state@128.
  {
    int c = (lane < K_) ? lane : last;
    for (int k = 0; k < 128; ++k) {
      int t = (lane < K_) ? (128 - k) : (255 - k);
      bool act = (lane < K_) || (lane == 63 && k <= 126);
      if (act) {
        c = bp[c][t];
        if (lane < K_) spec[lane][t - 1] = (unsigned char)c;
        else if (t >= 129) path_s[t - 1] = c;   // covers 128..254
      }
    }
  }
  asm volatile("s_waitcnt lgkmcnt(0)" ::: "memory");

  {
    int sstar = path_s[128];
#pragma unroll
    for (int q2 = 0; q2 < 2; ++q2) {
      int t = q2 * 64 + lane;
      path_s[t] = (int)spec[sstar][t];
    }
    if (lane == 0) path_s[S_ - 1] = last;
  }
  asm volatile("s_waitcnt lgkmcnt(0)" ::: "memory");

  int* o = out + (size_t)b * S_;
#pragma unroll
  for (int q2 = 0; q2 < 4; ++q2) o[q2 * 64 + lane] = path_s[q2 * 64 + lane];
}

extern "C" void kernel_launch(void* const* d_in, const int* in_sizes, int n_in,
                              void* d_out, int out_size, void* d_ws, size_t ws_size,
                              hipStream_t stream) {
  (void)in_sizes; (void)n_in; (void)out_size; (void)d_ws; (void)ws_size;
  const float* X  = (const float*)d_in[0];
  const float* W  = (const float*)d_in[1];
  const float* Tr = (const float*)d_in[2];
  int* outp = (int*)d_out;
  crf_fused<<<B_, 256, 0, stream>>>(X, W, Tr, outp);
}

// Round 13
// 157.475 us; speedup vs baseline: 2.9914x; 2.9914x over previous
//
#include <hip/hip_runtime.h>

#define B_ 1024
#define S_ 256
#define D_ 128
#define K_ 26

// Fully-fused streamed CRF: one 64-lane wave per chain. Emissions are computed
// inside the recurrence loop (r1-proven W-in-reg dot layout), X rows streamed
// global -> reg -> 4-slot LDS ring at distance 2-3. Recurrence/backtrack are the
// r11-proven bodies verbatim. No workspace, single launch.
__global__ __launch_bounds__(64) void crf_stream(
    const float* __restrict__ X, const float* __restrict__ W,
    const float* __restrict__ Tr, int* __restrict__ out)
{
  __shared__ __align__(16) float ring[4][D_];      //  2048 B X-row ring
  __shared__ __align__(16) float pub[28];          //   112 B
  __shared__ unsigned char bp[K_][260];            //  6760 B
  __shared__ unsigned char spec[K_][132];          //  3432 B
  __shared__ int path_s[S_];                       //  1024 B (~13.4 KB total)

  const int lane = threadIdx.x;
  const int j    = lane & 31;
  const int h    = lane >> 5;
  const int jc   = (j < K_) ? j : (K_ - 1);
  const int b    = blockIdx.x;

  // r1 layout: w[d] = W[jc][h*64 + d]
  float w[64];
  {
    const float4* wp = reinterpret_cast<const float4*>(W + jc * D_ + h * 64);
#pragma unroll
    for (int q = 0; q < 16; ++q) {
      float4 v4 = wp[q];
      w[4*q+0] = v4.x; w[4*q+1] = v4.y; w[4*q+2] = v4.z; w[4*q+3] = v4.w;
    }
  }
  float tc[K_];
#pragma unroll
  for (int i = 0; i < K_; ++i) tc[i] = Tr[i * K_ + jc];

  const float* xb = X + (size_t)b * (S_ * D_);

  // X stream helpers: lane owns bytes [8*lane, 8*lane+8) of each row
  auto ldrow = [&](int t) -> float2 {
    return *reinterpret_cast<const float2*>(xb + (size_t)t * D_ + 2 * lane);
  };
  auto wrow = [&](int slot, float2 g) {
    *reinterpret_cast<float2*>(&ring[slot][2 * lane]) = g;
  };
  // r1-exact emission dot: per-half 4-split, pairwise combine, xor-32 merge
  auto dotrow = [&](int slot) -> float {
    float a0 = 0.f, a1 = 0.f, a2 = 0.f, a3 = 0.f;
    const float4* rp = reinterpret_cast<const float4*>(&ring[slot][h * 64]);
#pragma unroll
    for (int q = 0; q < 16; ++q) {
      float4 x4 = rp[q];
      a0 = fmaf(x4.x, w[4*q+0], a0);
      a1 = fmaf(x4.y, w[4*q+1], a1);
      a2 = fmaf(x4.z, w[4*q+2], a2);
      a3 = fmaf(x4.w, w[4*q+3], a3);
    }
    float p = (a0 + a1) + (a2 + a3);
    return p + __shfl_xor(p, 32, 64);
  };

  // ---- prologue: stage rows 0..2 in ring, row 3 in regs
  float2 g0 = ldrow(0), g1 = ldrow(1), g2 = ldrow(2), g3 = ldrow(3);
  wrow(0, g0); wrow(1, g1); wrow(2, g2);
  float2 gs = g3;
  asm volatile("" ::: "memory");

  float delta = dotrow(0);                         // e[0][jc]  (t = 0)
  if (lane < 28) pub[lane] = -3.4e38f;
  if (lane < K_) pub[lane] = delta;
  asm volatile("" ::: "memory");

  float4 raw[7];
  {
    const float4* p = reinterpret_cast<const float4*>(pub);
#pragma unroll
    for (int q = 0; q < 7; ++q) raw[q] = p[q];     // uniform broadcast reads
  }
  float e_cur = dotrow(1);                         // e[1], consumed at t=1

  for (int t = 1; t < S_; ++t) {
    // raw holds delta(t-1)
    float v[K_ + 2];
#pragma unroll
    for (int q = 0; q < 7; ++q) {
      v[4*q+0] = raw[q].x;
      v[4*q+1] = raw[q].y;
      v[4*q+2] = raw[q].z;
      v[4*q+3] = raw[q].w;
    }
#pragma unroll
    for (int i = 0; i < K_; ++i) v[i] += tc[i];

    // value path: max3 tree (exact)
    float m[9];
#pragma unroll
    for (int i = 0; i < 8; ++i) m[i] = fmaxf(fmaxf(v[3*i], v[3*i+1]), v[3*i+2]);
    m[8] = fmaxf(v[24], v[25]);
    float n0 = fmaxf(fmaxf(m[0], m[1]), m[2]);
    float n1 = fmaxf(fmaxf(m[3], m[4]), m[5]);
    float n2 = fmaxf(fmaxf(m[6], m[7]), m[8]);
    float best = fmaxf(fmaxf(n0, n1), n2);

    delta = best + e_cur;                          // same op order as reference

    // publish delta(t); fence; issue next gather (same-wave DS in-order)
    if (lane < K_) pub[lane] = delta;
    asm volatile("" ::: "memory");
    {
      const float4* p = reinterpret_cast<const float4*>(pub);
#pragma unroll
      for (int q = 0; q < 7; ++q) raw[q] = p[q];
    }

    // emission for t+1 (fills gather stall; ring[(t+1)&3] written at step t-1)
    e_cur = dotrow((t + 1) & 3);

    // stream: row t+2 reg->LDS, then issue global load of row t+3
    wrow((t + 2) & 3, gs);
    asm volatile("" ::: "memory");
    int tl = (t + 3 < S_) ? (t + 3) : (S_ - 1);
    gs = ldrow(tl);

    // argmax (off critical path): first i with v[i]==best, register-light
    int idx = 63;
#pragma unroll
    for (int i = K_ - 1; i >= 0; --i) idx = (v[i] == best) ? i : idx;
    if (lane < K_) bp[lane][t] = (unsigned char)idx;
  }

  // final first-argmax over delta(255) (raw holds it, uniform on all lanes)
  int last;
  {
    float v[K_];
#pragma unroll
    for (int q = 0; q < 7; ++q) {
      if (4*q+0 < K_) v[4*q+0] = raw[q].x;
      if (4*q+1 < K_) v[4*q+1] = raw[q].y;
      if (4*q+2 < K_) v[4*q+2] = raw[q].z;
      if (4*q+3 < K_) v[4*q+3] = raw[q].w;
    }
    float bf = v[0];
#pragma unroll
    for (int i = 1; i < K_; ++i) bf = fmaxf(bf, v[i]);
    int iA = 63;
#pragma unroll
    for (int i = K_ - 1; i >= 0; --i) iA = (v[i] == bf) ? i : iA;
    last = iA;
  }

  __syncthreads();

  // backtrack: real chain (lane 63) t=255..129 concurrent with 26 speculative
  // chains (lanes 0..25) covering t=128..1 for every possible state@128.
  {
    int c = (lane < K_) ? lane : last;
    for (int k = 0; k < 128; ++k) {
      int t = (lane < K_) ? (128 - k) : (255 - k);
      bool act = (lane < K_) || (lane == 63 && k <= 126);
      if (act) {
        c = bp[c][t];
        if (lane < K_) spec[lane][t - 1] = (unsigned char)c;
        else if (t >= 129) path_s[t - 1] = c;   // covers 128..254
      }
    }
  }
  __syncthreads();

  {
    int sstar = path_s[128];
#pragma unroll
    for (int q2 = 0; q2 < 2; ++q2) {
      int t = q2 * 64 + lane;
      path_s[t] = (int)spec[sstar][t];
    }
    if (lane == 0) path_s[S_ - 1] = last;
  }
  __syncthreads();

  int* o = out + (size_t)b * S_;
#pragma unroll
  for (int q2 = 0; q2 < 4; ++q2) o[q2 * 64 + lane] = path_s[q2 * 64 + lane];
}

extern "C" void kernel_launch(void* const* d_in, const int* in_sizes, int n_in,
                              void* d_out, int out_size, void* d_ws, size_t ws_size,
                              hipStream_t stream) {
  (void)in_sizes; (void)n_in; (void)out_size; (void)d_ws; (void)ws_size;
  const float* X  = (const float*)d_in[0];
  const float* W  = (const float*)d_in[1];
  const float* Tr = (const float*)d_in[2];
  int* outp = (int*)d_out;
  crf_stream<<<B_, 64, 0, stream>>>(X, W, Tr, outp);
}

// Round 14
// 120.923 us; speedup vs baseline: 3.8956x; 1.3023x over previous
//
#include <hip/hip_runtime.h>

#define B_ 1024
#define S_ 256
#define D_ 128
#define K_ 26
#define EST 27   // e_lds row stride (odd -> conflict-free)

// Producer/consumer fused CRF: one block = 2 waves per chain.
// Wave 1 (producer): all 256 emission rows -> e_lds (r13-proven dot layout,
//   bit-identical e values), progress counter published after each row.
// Wave 0 (consumer): r11/r13-proven recurrence with NO emission work, polling
//   the counter every 16 steps; then r12-proven fence-only backtrack.
__global__ __launch_bounds__(128, 2) void crf_pc(
    const float* __restrict__ X, const float* __restrict__ W,
    const float* __restrict__ Tr, int* __restrict__ out)
{
  __shared__ __align__(16) float e_lds[S_ * EST];   // 27648 B (aliased in phase 3)
  __shared__ __align__(16) float ring[2][D_];       //  1024 B producer dbuf
  __shared__ __align__(16) float pub[28];           //   112 B
  __shared__ unsigned char bp[K_][260];             //  6760 B
  __shared__ int prog[4];                           //    16 B  (~35.6 KB total)

  const int tid  = threadIdx.x;
  const int lane = tid & 63;
  const int b    = blockIdx.x;

  if (tid == 0) prog[0] = 0;
  __syncthreads();                                  // both waves alive only here

  if (tid >= 64) {
    // ---------------- producer wave ----------------
    const int j  = lane & 31;
    const int h  = lane >> 5;
    const int jc = (j < K_) ? j : (K_ - 1);
    float w[64];                                    // w[d] = W[jc][h*64+d]
    {
      const float4* wp = reinterpret_cast<const float4*>(W + jc * D_ + h * 64);
#pragma unroll
      for (int q = 0; q < 16; ++q) {
        float4 v4 = wp[q];
        w[4*q+0] = v4.x; w[4*q+1] = v4.y; w[4*q+2] = v4.z; w[4*q+3] = v4.w;
      }
    }
    const float* xb = X + (size_t)b * (S_ * D_);
    float2 g = *reinterpret_cast<const float2*>(xb + 2 * lane);
    *reinterpret_cast<float2*>(&ring[0][2 * lane]) = g;
    g = *reinterpret_cast<const float2*>(xb + D_ + 2 * lane);
    asm volatile("" ::: "memory");

    for (int r = 0; r < S_; ++r) {
      const int cur = r & 1;
      float a0 = 0.f, a1 = 0.f, a2 = 0.f, a3 = 0.f;
      const float4* rp = reinterpret_cast<const float4*>(&ring[cur][h * 64]);
#pragma unroll
      for (int q = 0; q < 16; ++q) {
        float4 x4 = rp[q];
        a0 = fmaf(x4.x, w[4*q+0], a0);
        a1 = fmaf(x4.y, w[4*q+1], a1);
        a2 = fmaf(x4.z, w[4*q+2], a2);
        a3 = fmaf(x4.w, w[4*q+3], a3);
      }
      float p = (a0 + a1) + (a2 + a3);
      float e = p + __shfl_xor(p, 32, 64);          // r13-exact emission bits
      if (r + 1 < S_) *reinterpret_cast<float2*>(&ring[cur ^ 1][2 * lane]) = g;
      if (r + 2 < S_)
        g = *reinterpret_cast<const float2*>(xb + (size_t)(r + 2) * D_ + 2 * lane);
      if (h == 0 && j < K_) e_lds[r * EST + j] = e;
      asm volatile("" ::: "memory");                // data before counter
      if (lane == 0) *(volatile int*)&prog[0] = r + 1;
    }
    return;                                         // producer exits; no barriers after
  }

  // ---------------- consumer wave ----------------
  const int jc = (lane < K_) ? lane : (K_ - 1);
  float tc[K_];
#pragma unroll
  for (int i = 0; i < K_; ++i) tc[i] = Tr[i * K_ + jc];

  volatile int* vprog = prog;
#define WAIT_ROWS(n) do { while (*vprog < (n)) {} asm volatile("" ::: "memory"); } while (0)

  WAIT_ROWS(2);
  float delta = e_lds[jc];                          // t = 0
  if (lane < 28) pub[lane] = -3.4e38f;
  if (lane < K_) pub[lane] = delta;
  asm volatile("" ::: "memory");

  float4 raw[7];
  {
    const float4* p = reinterpret_cast<const float4*>(pub);
#pragma unroll
    for (int q = 0; q < 7; ++q) raw[q] = p[q];      // uniform broadcast reads
  }
  float ev_cur = e_lds[EST + jc];                   // e[1][jc]

  for (int ch = 0; ch < 16; ++ch) {
    const int tend = 16 * (ch + 1);
    const int need = (tend + 1 < S_) ? (tend + 1) : S_;
    WAIT_ROWS(need);                                // rows 0..tend ready
    for (int t = (ch == 0 ? 1 : 16 * ch); t < tend; ++t) {
      float v[K_ + 2];
#pragma unroll
      for (int q = 0; q < 7; ++q) {
        v[4*q+0] = raw[q].x; v[4*q+1] = raw[q].y;
        v[4*q+2] = raw[q].z; v[4*q+3] = raw[q].w;
      }
#pragma unroll
      for (int i = 0; i < K_; ++i) v[i] += tc[i];

      float m[9];
#pragma unroll
      for (int i = 0; i < 8; ++i)
        m[i] = fmaxf(fmaxf(v[3*i], v[3*i+1]), v[3*i+2]);
      m[8] = fmaxf(v[24], v[25]);
      float n0 = fmaxf(fmaxf(m[0], m[1]), m[2]);
      float n1 = fmaxf(fmaxf(m[3], m[4]), m[5]);
      float n2 = fmaxf(fmaxf(m[6], m[7]), m[8]);
      float best = fmaxf(fmaxf(n0, n1), n2);

      delta = best + ev_cur;                        // same op order as reference

      if (lane < K_) pub[lane] = delta;             // publish; fence; gather
      asm volatile("" ::: "memory");
      {
        const float4* p = reinterpret_cast<const float4*>(pub);
#pragma unroll
        for (int q = 0; q < 7; ++q) raw[q] = p[q];
      }

      int tn = (t + 1 < S_) ? (t + 1) : (S_ - 1);
      ev_cur = e_lds[tn * EST + jc];

      int idx = 63;                                 // first-max (jnp.argmax ties)
#pragma unroll
      for (int i = K_ - 1; i >= 0; --i) idx = (v[i] == best) ? i : idx;
      if (lane < K_) bp[lane][t] = (unsigned char)idx;
    }
  }

  // final first-argmax over delta(255)
  int last;
  {
    float v[K_];
#pragma unroll
    for (int q = 0; q < 7; ++q) {
      if (4*q+0 < K_) v[4*q+0] = raw[q].x;
      if (4*q+1 < K_) v[4*q+1] = raw[q].y;
      if (4*q+2 < K_) v[4*q+2] = raw[q].z;
      if (4*q+3 < K_) v[4*q+3] = raw[q].w;
    }
    float bf = v[0];
#pragma unroll
    for (int i = 1; i < K_; ++i) bf = fmaxf(bf, v[i]);
    int iA = 63;
#pragma unroll
    for (int i = K_ - 1; i >= 0; --i) iA = (v[i] == bf) ? i : iA;
    last = iA;
  }

  asm volatile("s_waitcnt lgkmcnt(0)" ::: "memory");   // bp writes drained

  // phase 3: backtrack (r12-proven, fence-only). e_lds is dead -> alias into it.
  unsigned char (*spec)[132] = reinterpret_cast<unsigned char (*)[132]>(e_lds); // 3432 B
  int* path_s = reinterpret_cast<int*>(reinterpret_cast<char*>(e_lds) + 4096);  // 1024 B

  {
    int c = (lane < K_) ? lane : last;
    for (int k = 0; k < 128; ++k) {
      int t = (lane < K_) ? (128 - k) : (255 - k);
      bool act = (lane < K_) || (lane == 63 && k <= 126);
      if (act) {
        c = bp[c][t];
        if (lane < K_) spec[lane][t - 1] = (unsigned char)c;
        else if (t >= 129) path_s[t - 1] = c;       // covers 128..254
      }
    }
  }
  asm volatile("s_waitcnt lgkmcnt(0)" ::: "memory");

  {
    int sstar = path_s[128];
#pragma unroll
    for (int q2 = 0; q2 < 2; ++q2) {
      int t = q2 * 64 + lane;
      path_s[t] = (int)spec[sstar][t];
    }
    if (lane == 0) path_s[S_ - 1] = last;
  }
  asm volatile("s_waitcnt lgkmcnt(0)" ::: "memory");

  int* o = out + (size_t)b * S_;
#pragma unroll
  for (int q2 = 0; q2 < 4; ++q2) o[q2 * 64 + lane] = path_s[q2 * 64 + lane];
#undef WAIT_ROWS
}

extern "C" void kernel_launch(void* const* d_in, const int* in_sizes, int n_in,
                              void* d_out, int out_size, void* d_ws, size_t ws_size,
                              hipStream_t stream) {
  (void)in_sizes; (void)n_in; (void)out_size; (void)d_ws; (void)ws_size;
  const float* X  = (const float*)d_in[0];
  const float* W  = (const float*)d_in[1];
  const float* Tr = (const float*)d_in[2];
  int* outp = (int*)d_out;
  crf_pc<<<B_, 128, 0, stream>>>(X, W, Tr, outp);
}